// Round 2
// baseline (95.250 us; speedup 1.0000x reference)
//
#include <hip/hip_runtime.h>

// PatchChamferDistance: B=32, G=64, P=256, D=3  ->  BG=2048 patches.
// dist2[i][j] = ||p_i||^2 + ||t_j||^2 - 2 p_i.t_j (clamped >= 0)
// out = mean over patches of (mean_i min_j dist2 + mean_j min_i dist2)
//
// Strategy (round 2): the j-stream is wave-uniform, so feed it through the
// SCALAR pipe (s_load) instead of LDS (round 1 was DS-pipe-bound 1.5x).
// - grid (2048 patches, 2 directions): direction from blockIdx.y keeps the
//   stream pointer uniform for the compiler's scalar-load selection.
// - 2 waves/block split the 256-long j-range (128 each) -> 32 waves/CU.
// - queries: 4 points/lane in VGPRs as (-2x,-2y,-2z) + norm.
// - inner: per j-pair, 6 scalar floats + 2 norms (3 VALU each) + 24 fma +
//   4 v_min3 = 34 VALU / 2j. Zero DS traffic in the loop.

#define NPATCH 2048
#define NPTS   256

__global__ __launch_bounds__(128, 8) void chamfer_dir_kernel(
    const float* __restrict__ pred,
    const float* __restrict__ tgt,
    float* __restrict__ partial)   // [NPATCH*2]
{
    __shared__ float mbuf[2][NPTS];

    const int patch = blockIdx.x;
    const int dir   = blockIdx.y;  // 0: fwd (queries=pred), 1: bwd (queries=tgt)
    const float* __restrict__ qb = (dir == 0 ? pred : tgt) + (size_t)patch * (NPTS * 3);
    const float* __restrict__ sb = (dir == 0 ? tgt : pred) + (size_t)patch * (NPTS * 3);

    const int tid  = threadIdx.x;
    const int wave = __builtin_amdgcn_readfirstlane(tid >> 6);  // uniform wave id
    const int lane = tid & 63;

    // 4 query points per lane, folded as (-2x,-2y,-2z) with norm on the side.
    float qx[4], qy[4], qz[4], qn[4], m[4];
#pragma unroll
    for (int q = 0; q < 4; ++q) {
        const int p = lane + 64 * q;
        const float x = qb[3 * p + 0];
        const float y = qb[3 * p + 1];
        const float z = qb[3 * p + 2];
        qx[q] = -2.0f * x;
        qy[q] = -2.0f * y;
        qz[q] = -2.0f * z;
        qn[q] = fmaf(z, z, fmaf(y, y, x * x));
        m[q]  = 1e30f;
    }

    // Each wave streams half the points: 64 j-pairs, uniform addresses.
    const float* __restrict__ s0 = sb + wave * (NPTS / 2) * 3;
#pragma unroll 4
    for (int jp = 0; jp < NPTS / 4; ++jp) {
        const float ax = s0[6 * jp + 0];
        const float ay = s0[6 * jp + 1];
        const float az = s0[6 * jp + 2];
        const float bx = s0[6 * jp + 3];
        const float by = s0[6 * jp + 4];
        const float bz = s0[6 * jp + 5];
        const float an = fmaf(az, az, fmaf(ay, ay, ax * ax));
        const float bn = fmaf(bz, bz, fmaf(by, by, bx * bx));
#pragma unroll
        for (int q = 0; q < 4; ++q) {
            const float da = fmaf(qx[q], ax, fmaf(qy[q], ay, fmaf(qz[q], az, an)));
            const float db = fmaf(qx[q], bx, fmaf(qy[q], by, fmaf(qz[q], bz, bn)));
            m[q] = fminf(m[q], fminf(da, db));   // -> v_min3_f32
        }
    }

    // Combine the two waves' partial mins, then add query norms + clamp.
#pragma unroll
    for (int q = 0; q < 4; ++q) mbuf[wave][lane + 64 * q] = m[q];
    __syncthreads();

    if (wave == 0) {
        float s = 0.0f;
#pragma unroll
        for (int q = 0; q < 4; ++q) {
            const float mm = fminf(mbuf[0][lane + 64 * q], mbuf[1][lane + 64 * q]);
            s += fmaxf(qn[q] + mm, 0.0f);
        }
#pragma unroll
        for (int off = 32; off > 0; off >>= 1)
            s += __shfl_down(s, off, 64);
        if (lane == 0) partial[patch * 2 + dir] = s;
    }
}

__global__ __launch_bounds__(256) void chamfer_reduce_kernel(
    const float* __restrict__ partial,
    float* __restrict__ out)
{
    __shared__ float red[4];
    const int tid = threadIdx.x;
    float s = 0.0f;
#pragma unroll
    for (int i = tid; i < NPATCH * 2; i += 256) s += partial[i];
#pragma unroll
    for (int off = 32; off > 0; off >>= 1)
        s += __shfl_down(s, off, 64);
    if ((tid & 63) == 0) red[tid >> 6] = s;
    __syncthreads();
    if (tid == 0)
        out[0] = (red[0] + red[1] + red[2] + red[3]) *
                 (1.0f / ((float)NPTS * (float)NPATCH));
}

extern "C" void kernel_launch(void* const* d_in, const int* in_sizes, int n_in,
                              void* d_out, int out_size, void* d_ws, size_t ws_size,
                              hipStream_t stream) {
    const float* pred = (const float*)d_in[0];
    const float* tgt  = (const float*)d_in[1];
    float* partial    = (float*)d_ws;      // 4096 floats = 16 KB scratch
    float* out        = (float*)d_out;

    chamfer_dir_kernel<<<dim3(NPATCH, 2), 128, 0, stream>>>(pred, tgt, partial);
    chamfer_reduce_kernel<<<1, 256, 0, stream>>>(partial, out);
}

// Round 3
// 83.904 us; speedup vs baseline: 1.1352x; 1.1352x over previous
//
#include <hip/hip_runtime.h>

// PatchChamferDistance: B=32, G=64, P=256, D=3 -> BG=2048 patches.
// dist2[i][j] = ||p_i||^2 + ||t_j||^2 - 2 p_i.t_j (clamped >= 0)
// out = mean over patches of (mean_i min_j + mean_j min_i)
//
// Round 3: back to LDS broadcast (round 2 scalar-pipe regressed), with
//  - SoA LDS planes (x,y,z per array), ds_read_b128 = 4 j's per plane read
//  - j-pair packed math: v_pk_fma_f32 via float2 ext-vectors (dual-rate fp32);
//    query scalars splat into both halves (op_sel, free)
//  - stream norms recomputed in packed VALU (cheaper than an n-plane read)
//  - 256-thread blocks: 4 waves = {fwd,bwd} x {j-half}
// Model: ~11.5 VALU-instr/j (vs 16 scalar) and 0.75 ds_read_b128/j (vs 1).

#define NPATCH 2048
#define NPTS   256

typedef float v2f __attribute__((ext_vector_type(2)));
typedef float v4f __attribute__((ext_vector_type(4)));

static __forceinline__ __device__ v2f splat2(float s) { return (v2f){s, s}; }
static __forceinline__ __device__ v2f fma2(v2f a, v2f b, v2f c) {
    return __builtin_elementwise_fma(a, b, c);
}
static __forceinline__ __device__ v2f min2(v2f a, v2f b) {
    return __builtin_elementwise_min(a, b);
}

__global__ __launch_bounds__(256, 4) void chamfer_patch_kernel(
    const float* __restrict__ pred,
    const float* __restrict__ tgt,
    float* __restrict__ partial)
{
    __shared__ float sP[3][NPTS];      // pred planes x,y,z
    __shared__ float sT[3][NPTS];      // tgt  planes x,y,z
    __shared__ float mhalf[2][NPTS];   // per-dir partial mins from half==1 waves
    __shared__ float red[2];

    const int patch = blockIdx.x;
    const int tid   = threadIdx.x;

    // Stage both point sets into SoA LDS planes.
    {
        const float* __restrict__ pb = pred + (size_t)patch * (NPTS * 3);
        const float* __restrict__ tb = tgt  + (size_t)patch * (NPTS * 3);
        float x = pb[3 * tid + 0], y = pb[3 * tid + 1], z = pb[3 * tid + 2];
        sP[0][tid] = x; sP[1][tid] = y; sP[2][tid] = z;
        x = tb[3 * tid + 0]; y = tb[3 * tid + 1]; z = tb[3 * tid + 2];
        sT[0][tid] = x; sT[1][tid] = y; sT[2][tid] = z;
    }
    __syncthreads();

    const int wave = tid >> 6;     // 0,1: forward  2,3: backward
    const int lane = tid & 63;
    const int dir  = wave >> 1;    // 0: queries=pred stream=tgt; 1: swapped
    const int half = wave & 1;     // which 128-long j half this wave streams

    const float (*Q)[NPTS] = (dir == 0) ? sP : sT;
    const float (*S)[NPTS] = (dir == 0) ? sT : sP;

    // 4 query points per lane: splat (-2x,-2y,-2z) for packed fma; norm scalar.
    v2f qx2[4], qy2[4], qz2[4], m2[4];
    float qn[4];
#pragma unroll
    for (int q = 0; q < 4; ++q) {
        const int p = lane + 64 * q;
        const float x = Q[0][p], y = Q[1][p], z = Q[2][p];
        qx2[q] = splat2(-2.0f * x);
        qy2[q] = splat2(-2.0f * y);
        qz2[q] = splat2(-2.0f * z);
        qn[q]  = fmaf(z, z, fmaf(y, y, x * x));
        m2[q]  = (v2f){1e30f, 1e30f};
    }

    const int jbase = half * (NPTS / 2);
    const float* __restrict__ Sx = &S[0][jbase];
    const float* __restrict__ Sy = &S[1][jbase];
    const float* __restrict__ Sz = &S[2][jbase];

#pragma unroll 2
    for (int jj = 0; jj < NPTS / 2; jj += 4) {
        const v4f tx4 = *(const v4f*)(Sx + jj);
        const v4f ty4 = *(const v4f*)(Sy + jj);
        const v4f tz4 = *(const v4f*)(Sz + jj);

        // low j-pair
        {
            const v2f tx = {tx4.x, tx4.y}, ty = {ty4.x, ty4.y}, tz = {tz4.x, tz4.y};
            const v2f tn = fma2(tz, tz, fma2(ty, ty, tx * tx));
#pragma unroll
            for (int q = 0; q < 4; ++q) {
                v2f d = fma2(qx2[q], tx, tn);
                d = fma2(qy2[q], ty, d);
                d = fma2(qz2[q], tz, d);
                m2[q] = min2(m2[q], d);
            }
        }
        // high j-pair
        {
            const v2f tx = {tx4.z, tx4.w}, ty = {ty4.z, ty4.w}, tz = {tz4.z, tz4.w};
            const v2f tn = fma2(tz, tz, fma2(ty, ty, tx * tx));
#pragma unroll
            for (int q = 0; q < 4; ++q) {
                v2f d = fma2(qx2[q], tx, tn);
                d = fma2(qy2[q], ty, d);
                d = fma2(qz2[q], tz, d);
                m2[q] = min2(m2[q], d);
            }
        }
    }

    // Waves covering the upper j-half publish their per-query mins.
    if (half == 1) {
#pragma unroll
        for (int q = 0; q < 4; ++q)
            mhalf[dir][lane + 64 * q] = fminf(m2[q].x, m2[q].y);
    }
    __syncthreads();

    if (half == 0) {
        float s = 0.0f;
#pragma unroll
        for (int q = 0; q < 4; ++q) {
            const float mm = fminf(fminf(m2[q].x, m2[q].y),
                                   mhalf[dir][lane + 64 * q]);
            s += fmaxf(qn[q] + mm, 0.0f);
        }
#pragma unroll
        for (int off = 32; off > 0; off >>= 1)
            s += __shfl_down(s, off, 64);
        if (lane == 0) red[dir] = s;
    }
    __syncthreads();
    if (tid == 0) partial[patch] = red[0] + red[1];
}

__global__ __launch_bounds__(256) void chamfer_reduce_kernel(
    const float* __restrict__ partial,
    float* __restrict__ out)
{
    __shared__ float red[4];
    const int tid = threadIdx.x;
    float s = 0.0f;
#pragma unroll
    for (int i = tid; i < NPATCH; i += 256) s += partial[i];
#pragma unroll
    for (int off = 32; off > 0; off >>= 1)
        s += __shfl_down(s, off, 64);
    if ((tid & 63) == 0) red[tid >> 6] = s;
    __syncthreads();
    if (tid == 0)
        out[0] = (red[0] + red[1] + red[2] + red[3]) *
                 (1.0f / ((float)NPTS * (float)NPATCH));
}

extern "C" void kernel_launch(void* const* d_in, const int* in_sizes, int n_in,
                              void* d_out, int out_size, void* d_ws, size_t ws_size,
                              hipStream_t stream) {
    const float* pred = (const float*)d_in[0];
    const float* tgt  = (const float*)d_in[1];
    float* partial    = (float*)d_ws;      // 2048 floats = 8 KB scratch
    float* out        = (float*)d_out;

    chamfer_patch_kernel<<<NPATCH, 256, 0, stream>>>(pred, tgt, partial);
    chamfer_reduce_kernel<<<1, 256, 0, stream>>>(partial, out);
}